// Round 7
// baseline (426.422 us; speedup 1.0000x reference)
//
#include <hip/hip_runtime.h>
#include <stdint.h>

// Problem constants
#define B_  2
#define T_  2048
#define C_  2048
#define H_  16
#define D_  128
#define BH_ 32        // B*H
#define M_  4096      // B*T

typedef __attribute__((ext_vector_type(8))) __bf16  bf16x8;
typedef __attribute__((ext_vector_type(4))) float   floatx4;
typedef __attribute__((ext_vector_type(4))) ushort  ushortx4;

__device__ __forceinline__ ushort f2bf(float f) {
    union { float f; uint32_t u; } v; v.f = f;
    return (ushort)((v.u + 0x7fffu + ((v.u >> 16) & 1u)) >> 16);
}

__device__ __forceinline__ float bf2f(ushort u) {
    union { uint32_t u; float f; } v; v.u = ((uint32_t)u) << 16;
    return v.f;
}

__device__ __forceinline__ floatx4 mfma_bf16(bf16x8 a, bf16x8 b, floatx4 c) {
    return __builtin_amdgcn_mfma_f32_16x16x32_bf16(a, b, c, 0, 0, 0);
}

// async global->LDS, 16B per lane; lds dest = wave-uniform base + lane*16
__device__ __forceinline__ void async16(const ushort* g, ushort* l) {
    __builtin_amdgcn_global_load_lds(
        (const __attribute__((address_space(1))) uint32_t*)g,
        (__attribute__((address_space(3))) uint32_t*)l, 16, 0, 0);
}

// ---------------------------------------------------------------------------
// x f32 -> bf16 (vectorized 4-wide)
// ---------------------------------------------------------------------------
__global__ __launch_bounds__(256) void convert_bf16(
    const float* __restrict__ X, ushort* __restrict__ Xb)
{
    const int i = blockIdx.x * 256 + threadIdx.x;
    const float4 v = ((const float4*)X)[i];
    ushortx4 p = { f2bf(v.x), f2bf(v.y), f2bf(v.z), f2bf(v.w) };
    ((ushortx4*)Xb)[i] = p;
}

// ---------------------------------------------------------------------------
// Transpose + convert: W f32 [K][N] -> Wt bf16 [N][K]
// ---------------------------------------------------------------------------
__global__ __launch_bounds__(256) void transpose_w(
    const float* __restrict__ W, ushort* __restrict__ Wt, int Kdim, int Ndim)
{
    __shared__ float tile[32][33];
    const int n0 = blockIdx.x * 32, k0 = blockIdx.y * 32;
    const int tx = threadIdx.x, ty = threadIdx.y;
    #pragma unroll
    for (int j = 0; j < 4; j++)
        tile[ty + j*8][tx] = W[(size_t)(k0 + ty + j*8) * Ndim + n0 + tx];
    __syncthreads();
    #pragma unroll
    for (int j = 0; j < 4; j++)
        Wt[(size_t)(n0 + ty + j*8) * Kdim + k0 + tx] = f2bf(tile[tx][ty + j*8]);
}

// ---------------------------------------------------------------------------
// Plain GEMM (m97 structure): C[M][N] = A_bf16 @ Bt_bf16^T, C f32. (proj)
// ---------------------------------------------------------------------------
#define BM 128
#define BN 128
#define BK 32

__global__ __launch_bounds__(256) void gemm_bt(
    const ushort* __restrict__ A, const ushort* __restrict__ Bt,
    float* __restrict__ Co, int Ndim, int Kdim)
{
    __shared__ __align__(16) ushort As[BM * BK];
    __shared__ __align__(16) ushort Bs[BN * BK];
    const int tid  = threadIdx.x;
    const int lane = tid & 63;
    const int w    = tid >> 6;
    const int wm   = (w >> 1) * 64;
    const int wn   = (w & 1) * 64;
    const int lr   = lane & 15;
    const int quad = lane >> 4;
    const int srow = lane >> 2;
    const int soff = (lane & 3) * 8;

    const ushort* Ablk = A  + (size_t)(blockIdx.y * BM) * Kdim;
    const ushort* Bblk = Bt + (size_t)(blockIdx.x * BN) * Kdim;

    floatx4 acc[4][4];
    #pragma unroll
    for (int i = 0; i < 4; i++)
        #pragma unroll
        for (int j = 0; j < 4; j++)
            acc[i][j] = (floatx4){0.f, 0.f, 0.f, 0.f};

    for (int k0 = 0; k0 < Kdim; k0 += BK) {
        __syncthreads();
        #pragma unroll
        for (int j = 0; j < 2; j++) {
            const int row = w * 32 + j * 16 + srow;
            async16(Ablk + (size_t)row * Kdim + k0 + soff,
                    As + (w * 32 + j * 16) * BK);
            async16(Bblk + (size_t)row * Kdim + k0 + soff,
                    Bs + (w * 32 + j * 16) * BK);
        }
        __syncthreads();

        bf16x8 af[4], bfr[4];
        #pragma unroll
        for (int mi = 0; mi < 4; mi++)
            af[mi] = *(const bf16x8*)(&As[(wm + mi*16 + lr) * BK + quad * 8]);
        #pragma unroll
        for (int ni = 0; ni < 4; ni++)
            bfr[ni] = *(const bf16x8*)(&Bs[(wn + ni*16 + lr) * BK + quad * 8]);
        #pragma unroll
        for (int mi = 0; mi < 4; mi++)
            #pragma unroll
            for (int ni = 0; ni < 4; ni++)
                acc[mi][ni] = mfma_bf16(af[mi], bfr[ni], acc[mi][ni]);
    }

    const size_t row0 = (size_t)blockIdx.y * BM + wm;
    const size_t col0 = (size_t)blockIdx.x * BN + wn;
    #pragma unroll
    for (int mi = 0; mi < 4; mi++)
        #pragma unroll
        for (int ni = 0; ni < 4; ni++)
            #pragma unroll
            for (int r = 0; r < 4; r++)
                Co[(row0 + mi*16 + quad*4 + r) * (size_t)Ndim + col0 + ni*16 + lr]
                    = acc[mi][ni][r];
}

// ---------------------------------------------------------------------------
// Fused QKV GEMM (exact R0 version): epilogue produces flash-ready tensors.
// ---------------------------------------------------------------------------
__global__ __launch_bounds__(256) void gemm_qkv(
    const ushort* __restrict__ A, const ushort* __restrict__ Bt,
    const float* __restrict__ cosb, const float* __restrict__ sinb,
    ushort* __restrict__ qb, ushort* __restrict__ kbf, ushort* __restrict__ vt)
{
    __shared__ __align__(16) ushort smem[17408];   // 34,816 B
    ushort* As = smem;          // 128*32
    ushort* Bs = smem + 4096;   // 128*32

    const int tid  = threadIdx.x;
    const int lane = tid & 63;
    const int w    = tid >> 6;
    const int wm   = (w >> 1) * 64;
    const int wn   = (w & 1) * 64;
    const int lr   = lane & 15;
    const int quad = lane >> 4;
    const int srow = lane >> 2;
    const int soff = (lane & 3) * 8;

    const int Kdim = C_;
    const ushort* Ablk = A  + (size_t)(blockIdx.y * BM) * Kdim;
    const ushort* Bblk = Bt + (size_t)(blockIdx.x * BN) * Kdim;

    floatx4 acc[4][4];
    #pragma unroll
    for (int i = 0; i < 4; i++)
        #pragma unroll
        for (int j = 0; j < 4; j++)
            acc[i][j] = (floatx4){0.f, 0.f, 0.f, 0.f};

    for (int k0 = 0; k0 < Kdim; k0 += BK) {
        __syncthreads();
        #pragma unroll
        for (int j = 0; j < 2; j++) {
            const int row = w * 32 + j * 16 + srow;
            async16(Ablk + (size_t)row * Kdim + k0 + soff,
                    As + (w * 32 + j * 16) * BK);
            async16(Bblk + (size_t)row * Kdim + k0 + soff,
                    Bs + (w * 32 + j * 16) * BK);
        }
        __syncthreads();

        bf16x8 af[4], bfr[4];
        #pragma unroll
        for (int mi = 0; mi < 4; mi++)
            af[mi] = *(const bf16x8*)(&As[(wm + mi*16 + lr) * BK + quad * 8]);
        #pragma unroll
        for (int ni = 0; ni < 4; ni++)
            bfr[ni] = *(const bf16x8*)(&Bs[(wn + ni*16 + lr) * BK + quad * 8]);
        #pragma unroll
        for (int mi = 0; mi < 4; mi++)
            #pragma unroll
            for (int ni = 0; ni < 4; ni++)
                acc[mi][ni] = mfma_bf16(af[mi], bfr[ni], acc[mi][ni]);
    }

    // ---- epilogue ----
    const int h   = blockIdx.x & 15;
    const int qt  = blockIdx.x >> 4;
    const int b   = blockIdx.y >> 4;
    const int t0g = (blockIdx.y & 15) * 128;
    const int bh  = b * 16 + h;

    __syncthreads();   // all frag reads done before smem reuse

    if (qt < 2) {
        // acc -> LDS [t][136] bf16
        #pragma unroll
        for (int mi = 0; mi < 4; mi++)
            #pragma unroll
            for (int ni = 0; ni < 4; ni++)
                #pragma unroll
                for (int r = 0; r < 4; r++) {
                    const int t = wm + mi*16 + quad*4 + r;
                    const int d = wn + ni*16 + lr;
                    smem[t * 136 + d] = f2bf(acc[mi][ni][r]);
                }
        __syncthreads();

        // readback: thread -> row t = tid>>1, d-chunks [c0,c0+32) and +64
        const int t  = tid >> 1;
        const int c0 = (tid & 1) * 32;
        bf16x8 x1v[4], x2v[4];
        #pragma unroll
        for (int u = 0; u < 4; u++) {
            x1v[u] = *(const bf16x8*)(smem + t * 136 + c0 + u * 8);
            x2v[u] = *(const bf16x8*)(smem + t * 136 + 64 + c0 + u * 8);
        }
        const float4* cp4 = (const float4*)(cosb + (size_t)(t0g + t) * 64 + c0);
        const float4* sp4 = (const float4*)(sinb + (size_t)(t0g + t) * 64 + c0);
        ushort* outp = (qt == 0 ? qb : kbf) + ((size_t)bh * T_ + t0g + t) * D_;
        #pragma unroll
        for (int u = 0; u < 4; u++) {
            float cc[8], ss[8];
            *(float4*)(cc)     = cp4[u * 2];
            *(float4*)(cc + 4) = cp4[u * 2 + 1];
            *(float4*)(ss)     = sp4[u * 2];
            *(float4*)(ss + 4) = sp4[u * 2 + 1];
            ushortx4 lo0, lo1, hi0, hi1;
            #pragma unroll
            for (int e = 0; e < 8; e++) {
                const float x1 = (float)x1v[u][e];
                const float x2 = (float)x2v[u][e];
                const ushort vlo = f2bf(x1 * cc[e] - x2 * ss[e]);
                const ushort vhi = f2bf(x1 * ss[e] + x2 * cc[e]);
                if (e < 4) { lo0[e] = vlo; hi0[e] = vhi; }
                else       { lo1[e-4] = vlo; hi1[e-4] = vhi; }
            }
            *(ushortx4*)(outp + c0 + u*8)          = lo0;
            *(ushortx4*)(outp + c0 + u*8 + 4)      = lo1;
            *(ushortx4*)(outp + 64 + c0 + u*8)     = hi0;
            *(ushortx4*)(outp + 64 + c0 + u*8 + 4) = hi1;
        }
    } else {
        // v: acc -> LDS transposed [d][128], units swizzled by d
        #pragma unroll
        for (int mi = 0; mi < 4; mi++)
            #pragma unroll
            for (int ni = 0; ni < 4; ni++)
                #pragma unroll
                for (int r = 0; r < 4; r++) {
                    const int t = wm + mi*16 + quad*4 + r;
                    const int d = wn + ni*16 + lr;
                    smem[d * 128 + (t & 7) + 8 * ((t >> 3) ^ (d & 15))]
                        = f2bf(acc[mi][ni][r]);
                }
        __syncthreads();

        const int d    = tid >> 1;
        const int half = tid & 1;
        ushort* outp = vt + ((size_t)bh * D_ + d) * T_ + t0g + half * 64;
        #pragma unroll
        for (int u = 0; u < 8; u++) {
            const int gu = half * 8 + u;
            bf16x8 vv = *(const bf16x8*)(smem + d * 128 + 8 * (gu ^ (d & 15)));
            *(bf16x8*)(outp + u * 8) = vv;
        }
    }
}

// ---------------------------------------------------------------------------
// Cooperative causal flash attention, static-shift softmax.
// R7: 32 q-rows per wave (two 16-row groups, adjacent: qbase0, qbase0+16).
//   Every K fragment (af) and V fragment (vf) read from LDS feeds TWO MFMAs
//   (one per group) -> LDS bytes per MFMA halved; block-tile iteration count
//   halved (grid 512 = 16 m-tiles x 32 bh, exactly 2 blocks/CU).
//   With 64-aligned K-tiles, both groups of a wave are always active or
//   inactive together (one uniform skip branch per wave per tile).
//   Anti-correlated m mapping pairs long blocks with short ones on each CU
//   (nk sums ~const). Double-buffered K/V staging (issue-early) kept from R6.
// Output bf16 [M][C] so the proj GEMM consumes it directly.
// ---------------------------------------------------------------------------
__global__ __launch_bounds__(256, 2) void flash_attn(
    const ushort* __restrict__ qb, const ushort* __restrict__ kb,
    const ushort* __restrict__ vt, ushort* __restrict__ attnoutb)
{
    __shared__ __align__(16) ushort kt_s[2][64 * 128];   // [key][d], units ^key
    __shared__ __align__(16) ushort vt_s[2][128 * 64];   // [d][key], units ^d
    __shared__ __align__(16) ushort pl_s[4][2][16 * 40]; // per-wave, per-group P

    const int w    = threadIdx.x >> 6;
    const int lane = threadIdx.x & 63;
    const int lr   = lane & 15;
    const int quad = lane >> 4;

    const int bh = blockIdx.x & 31;
    const int zz = blockIdx.x >> 5;                  // 0..15
    const int mm = (zz < 8) ? (15 - zz) : (zz - 8);  // pair long with short
    const int qbase0 = mm * 128 + w * 32;            // group 0 rows
    const int qbase1 = qbase0 + 16;                  // group 1 rows
    const int nk = 2 * mm + 2;
    const int bb = bh >> 4, hh = bh & 15;

    const ushort* kbp = kb + (size_t)bh * T_ * D_;
    const ushort* vbp = vt + (size_t)bh * D_ * T_;
    ushort* pl0 = pl_s[w][0];
    ushort* pl1 = pl_s[w][1];

    const int krow4 = lane >> 4;
    const int kunit = lane & 15;
    const int vrow8 = lane >> 3;
    const int vunit = lane & 7;

    bf16x8 qf0[4], qf1[4];
    {
        const ushort* qrow0 = qb + ((size_t)bh * T_ + qbase0 + lr) * D_ + quad * 8;
        const ushort* qrow1 = qb + ((size_t)bh * T_ + qbase1 + lr) * D_ + quad * 8;
        #pragma unroll
        for (int kc = 0; kc < 4; kc++) {
            qf0[kc] = *(const bf16x8*)(qrow0 + kc * 32);
            qf1[kc] = *(const bf16x8*)(qrow1 + kc * 32);
        }
    }

    floatx4 o0[8], o1[8];
    #pragma unroll
    for (int dc = 0; dc < 8; dc++) {
        o0[dc] = (floatx4){0.f, 0.f, 0.f, 0.f};
        o1[dc] = (floatx4){0.f, 0.f, 0.f, 0.f};
    }
    floatx4 lac0 = (floatx4){0.f, 0.f, 0.f, 0.f};
    floatx4 lac1 = (floatx4){0.f, 0.f, 0.f, 0.f};

    const __bf16 one = (__bf16)1.0f;
    const bf16x8 ones = {one, one, one, one, one, one, one, one};
    const float SCL  = 0.08838834764831845f * 1.4426950408889634f;
    const float BIAS = 23.083120654223414f;

    // ---- prologue: stage tile 0 into buf 0 ----
    {
        #pragma unroll
        for (int j = 0; j < 4; j++) {
            const int row = w * 16 + j * 4 + krow4;
            const ushort* gp = kbp + (size_t)row * D_
                                   + ((kunit ^ (row & 15)) << 3);
            async16(gp, kt_s[0] + (w * 16 + j * 4) * 128);
        }
        #pragma unroll
        for (int j = 0; j < 4; j++) {
            const int row = w * 32 + j * 8 + vrow8;
            const ushort* gp = vbp + (size_t)row * T_
                                   + ((vunit ^ (row & 7)) << 3);
            async16(gp, vt_s[0] + (w * 32 + j * 8) * 64);
        }
    }
    __syncthreads();

    for (int kt = 0; kt < nk; ++kt) {
        const int bsel = kt & 1;
        const int kb0  = kt * 64;

        // ---- issue next tile's DMAs first (fly under compute) ----
        if (kt + 1 < nk) {
            const int kb1 = kb0 + 64;
            #pragma unroll
            for (int j = 0; j < 4; j++) {
                const int row = w * 16 + j * 4 + krow4;
                const ushort* gp = kbp + (size_t)(kb1 + row) * D_
                                       + ((kunit ^ (row & 15)) << 3);
                async16(gp, kt_s[bsel ^ 1] + (w * 16 + j * 4) * 128);
            }
            #pragma unroll
            for (int j = 0; j < 4; j++) {
                const int row = w * 32 + j * 8 + vrow8;
                const ushort* gp = vbp + (size_t)row * T_ + kb1
                                       + ((vunit ^ (row & 7)) << 3);
                async16(gp, vt_s[bsel ^ 1] + (w * 32 + j * 8) * 64);
            }
        }

        // ---- compute tile kt from buf bsel (skip if fully masked) ----
        if (kb0 <= qbase0 + 31) {
            const ushort* kbuf = kt_s[bsel];
            const ushort* vbuf = vt_s[bsel];

            #pragma unroll
            for (int half = 0; half < 2; ++half) {
                floatx4 st0[2], st1[2];
                #pragma unroll
                for (int jj = 0; jj < 2; ++jj) {
                    const int j = half * 2 + jj;
                    floatx4 s0 = (floatx4){0.f, 0.f, 0.f, 0.f};
                    floatx4 s1 = (floatx4){0.f, 0.f, 0.f, 0.f};
                    const int kl = j * 16 + lr;
                    #pragma unroll
                    for (int kc = 0; kc < 4; kc++) {
                        bf16x8 af = *(const bf16x8*)(
                            kbuf + kl * 128 + ((((kc << 2) | quad) ^ lr) << 3));
                        s0 = mfma_bf16(af, qf0[kc], s0);
                        s1 = mfma_bf16(af, qf1[kc], s1);
                    }
                    st0[jj] = s0;
                    st1[jj] = s1;
                }
                #pragma unroll
                for (int jj = 0; jj < 2; ++jj) {
                    const int kg0 = kb0 + (half * 2 + jj) * 16 + quad * 4;
                    float p0[4], p1[4];
                    #pragma unroll
                    for (int r = 0; r < 4; r++) {
                        float e0 = __builtin_amdgcn_exp2f(fmaf(st0[jj][r], SCL, -BIAS));
                        float e1 = __builtin_amdgcn_exp2f(fmaf(st1[jj][r], SCL, -BIAS));
                        p0[r] = (kg0 + r > qbase0 + lr) ? 0.f : e0;
                        p1[r] = (kg0 + r > qbase1 + lr) ? 0.f : e1;
                    }
                    uint2 pk0, pk1;
                    pk0.x = (uint32_t)f2bf(p0[0]) | ((uint32_t)f2bf(p0[1]) << 16);
                    pk0.y = (uint32_t)f2bf(p0[2]) | ((uint32_t)f2bf(p0[3]) << 16);
                    pk1.x = (uint32_t)f2bf(p1[0]) | ((uint32_t)f2bf(p1[1]) << 16);
                    pk1.y = (uint32_t)f2bf(p1[2]) | ((uint32_t)f2bf(p1[3]) << 16);
                    *(uint2*)(pl0 + lr * 40 + jj * 16 + quad * 4) = pk0;
                    *(uint2*)(pl1 + lr * 40 + jj * 16 + quad * 4) = pk1;
                }
                bf16x8 pf0 = *(const bf16x8*)(pl0 + lr * 40 + quad * 8);
                bf16x8 pf1 = *(const bf16x8*)(pl1 + lr * 40 + quad * 8);
                lac0 = mfma_bf16(pf0, ones, lac0);
                lac1 = mfma_bf16(pf1, ones, lac1);
                #pragma unroll
                for (int dc = 0; dc < 8; dc++) {
                    const int d = dc * 16 + lr;
                    bf16x8 vf = *(const bf16x8*)(
                        vbuf + d * 64 + ((((half << 2) | quad) ^ (lr & 7)) << 3));
                    o0[dc] = mfma_bf16(pf0, vf, o0[dc]);
                    o1[dc] = mfma_bf16(pf1, vf, o1[dc]);
                }
            }
        }

        // one barrier per iter: drains (overlapped) kt+1 DMAs and certifies
        // all waves done reading buf bsel before iter kt+2 overwrites it
        __syncthreads();
    }

    #pragma unroll
    for (int dc = 0; dc < 8; dc++)
        #pragma unroll
        for (int r = 0; r < 4; r++) {
            const int trow0 = qbase0 + quad * 4 + r;
            const int trow1 = qbase1 + quad * 4 + r;
            attnoutb[((size_t)(bb * T_ + trow0)) * C_ + hh * D_ + dc * 16 + lr]
                = f2bf(o0[dc][r] / lac0[r]);
            attnoutb[((size_t)(bb * T_ + trow1)) * C_ + hh * D_ + dc * 16 + lr]
                = f2bf(o1[dc][r] / lac1[r]);
        }
}

// ---------------------------------------------------------------------------
extern "C" void kernel_launch(void* const* d_in, const int* in_sizes, int n_in,
                              void* d_out, int out_size, void* d_ws, size_t ws_size,
                              hipStream_t stream)
{
    (void)in_sizes; (void)n_in; (void)out_size; (void)ws_size;
    const float* x     = (const float*)d_in[0];
    const float* cosb  = (const float*)d_in[1];
    const float* sinb  = (const float*)d_in[2];
    const float* Wqkv  = (const float*)d_in[3];
    const float* Wproj = (const float*)d_in[4];
    float* out = (float*)d_out;

    // Workspace (117,440,512 B used):
    //  xb   [M][C] bf16        @ 0          (16,777,216)
    //  Wtq  [3C][C] bf16       @ 16777216   (25,165,824)
    //  Wtp  [C][C] bf16        @ 41943040   ( 8,388,608)
    //  qb   [BH][T][D] bf16    @ 50331648   (16,777,216)
    //  kb   [BH][T][D] bf16    @ 67108864   (16,777,216)
    //  vt   [BH][D][T] bf16    @ 83886080   (16,777,216)
    //  attn [M][C] bf16        @ 100663296  (16,777,216)
    char* ws = (char*)d_ws;
    ushort* xb       = (ushort*)(ws);
    ushort* Wtq      = (ushort*)(ws + 16777216);
    ushort* Wtp      = (ushort*)(ws + 41943040);
    ushort* qb       = (ushort*)(ws + 50331648);
    ushort* kbf      = (ushort*)(ws + 67108864);
    ushort* vt       = (ushort*)(ws + 83886080);
    ushort* attnoutb = (ushort*)(ws + 100663296);

    dim3 tb32(32, 8);
    transpose_w<<<dim3(3 * C_ / 32, C_ / 32), tb32, 0, stream>>>(Wqkv, Wtq, C_, 3 * C_);
    transpose_w<<<dim3(C_ / 32, C_ / 32),     tb32, 0, stream>>>(Wproj, Wtp, C_, C_);
    convert_bf16<<<(M_ * C_ / 4) / 256, 256, 0, stream>>>(x, xb);

    gemm_qkv<<<dim3(3 * C_ / BN, M_ / BM), 256, 0, stream>>>(
        xb, Wtq, cosb, sinb, qb, kbf, vt);

    flash_attn<<<BH_ * 16, 256, 0, stream>>>(qb, kbf, vt, attnoutb);

    gemm_bt<<<dim3(C_ / BN, M_ / BM), 256, 0, stream>>>(attnoutb, Wtp, out, C_, C_);
}